// Round 7
// baseline (17467.175 us; speedup 1.0000x reference)
//
#include <hip/hip_runtime.h>
#include <hip/hip_bf16.h>

typedef unsigned short u16;
typedef unsigned long long u64;
typedef short short8 __attribute__((ext_vector_type(8)));
typedef float f32x4 __attribute__((ext_vector_type(4)));

#define S_ 500
#define B_ 128
#define T_ 250
#define H_ 512
#define K_ 128
#define V_ 128
#define VOC 1000
#define NSTEP 249   // T-1
#define NWG 128

#define H1ST_STRIDE 516                 // padded row stride (shorts): 4-bank rotation/row
#define OFF_H1ST   128000               // after vshare 500*128*2
#define OFF_EBUF   (OFF_H1ST + 33024)   // 32*516*2 = 33024 -> 161024
#define OFF_H2S    (OFF_EBUF + 2048)    // 163072
#define OFF_REDM   (OFF_H2S + 512)      // 163584
#define SMEM_BYTES (OFF_REDM + 64)      // 163648 <= 163840

__device__ __forceinline__ float bf2f(u16 u) {
    union { unsigned int i; float f; } x; x.i = ((unsigned int)u) << 16; return x.f;
}
__device__ __forceinline__ u16 f2bf(float f) {
    union { float f; unsigned int i; } x; x.f = f;
    unsigned int r = x.i + 0x7fffu + ((x.i >> 16) & 1u);
    return (u16)(r >> 16);
}
__device__ __forceinline__ float sigm(float x) { return 1.f / (1.f + __expf(-x)); }
__device__ __forceinline__ f32x4 mfma16(short8 a, short8 b, f32x4 c) {
    return __builtin_amdgcn_mfma_f32_16x16x32_bf16(a, b, c, 0, 0, 0);
}

// ---- agent-scope coherent (sc1, MALL-direct) state accessors, NO fences ----
__device__ __forceinline__ u64 ld_state8(const u16* p) {
    return __hip_atomic_load((const u64*)p, __ATOMIC_RELAXED, __HIP_MEMORY_SCOPE_AGENT);
}
__device__ __forceinline__ short8 ld_state16(const u16* p) {
    union { u64 q[2]; short8 s; } u;
    u.q[0] = ld_state8(p); u.q[1] = ld_state8(p + 4);
    return u.s;
}
__device__ __forceinline__ void st_state4(u16* p, unsigned v) {
    __hip_atomic_store((unsigned*)p, v, __ATOMIC_RELAXED, __HIP_MEMORY_SCOPE_AGENT);
}
__device__ __forceinline__ void st_pair(u16* p, float a, float b) {
    st_state4(p, (unsigned)f2bf(a) | ((unsigned)f2bf(b) << 16));
}

// Device-scope 2-level barrier, ALL RELAXED (no buffer_inv => L2 keeps read-only
// data resident). 8 leaves x 16 arrivals + root of 8. Visibility via sc1/MALL.
__device__ __forceinline__ void gbar(unsigned* bar, int wg) {
    __syncthreads();   // drains vmcnt: this WG's sc1 stores are MALL-acked before arrival
    if (threadIdx.x == 0) {
        unsigned* leaf = bar + (wg & 7) * 64;
        unsigned* root = bar + 512;
        unsigned* gen  = bar + 576;
        unsigned g = __hip_atomic_load(gen, __ATOMIC_RELAXED, __HIP_MEMORY_SCOPE_AGENT);
        unsigned a = __hip_atomic_fetch_add(leaf, 1u, __ATOMIC_RELAXED, __HIP_MEMORY_SCOPE_AGENT);
        if (a == 15u) {
            __hip_atomic_store(leaf, 0u, __ATOMIC_RELAXED, __HIP_MEMORY_SCOPE_AGENT);
            unsigned r = __hip_atomic_fetch_add(root, 1u, __ATOMIC_RELAXED, __HIP_MEMORY_SCOPE_AGENT);
            if (r == 7u) {
                __hip_atomic_store(root, 0u, __ATOMIC_RELAXED, __HIP_MEMORY_SCOPE_AGENT);
                __hip_atomic_store(gen, g + 1u, __ATOMIC_RELAXED, __HIP_MEMORY_SCOPE_AGENT);
            } else {
                while (__hip_atomic_load(gen, __ATOMIC_RELAXED, __HIP_MEMORY_SCOPE_AGENT) == g)
                    __builtin_amdgcn_s_sleep(1);
            }
        } else {
            while (__hip_atomic_load(gen, __ATOMIC_RELAXED, __HIP_MEMORY_SCOPE_AGENT) == g)
                __builtin_amdgcn_s_sleep(1);
        }
    }
    __syncthreads();
}

// ---------------- setup: pack weights ----------------
// W1f: MFMA-fragment layout, K=1152 (emb512|ctx128|h1 512), N=2048.
// W2gp: GEMV thread-pair layout: W2gp[(k*256+t)*2+slot] = W2cat[k][col(t,slot)]
//       col(t,0) = (t>>7)*256 + (t&127)  (gates i / g), col(t,1) = col(t,0)+128 (f / o).
// Woutf: MFMA layout K=256, N=1024 (cols >= 1000 zero).
__global__ __launch_bounds__(256) void pack_kernel(
    const float* __restrict__ w_ih1, const float* __restrict__ w_hh1,
    const float* __restrict__ b_ih1, const float* __restrict__ b_hh1,
    const float* __restrict__ w_ih2, const float* __restrict__ w_hh2,
    const float* __restrict__ b_ih2, const float* __restrict__ b_hh2,
    const float* __restrict__ w_out, const float* __restrict__ emb,
    u16* __restrict__ W1f, u16* __restrict__ W2gp, u16* __restrict__ Woutf,
    float* __restrict__ bias1, float* __restrict__ bias2p, u16* __restrict__ emb_bf,
    unsigned* __restrict__ bar)
{
    const int i0 = blockIdx.x * 256 + threadIdx.x;
    const int stride = gridDim.x * 256;
    for (int i = i0; i < 1024; i += stride)
        __hip_atomic_store(bar + i, 0u, __ATOMIC_RELAXED, __HIP_MEMORY_SCOPE_AGENT);
    for (int i = i0; i < 1152 * 2048; i += stride) {
        int k = i >> 11, n = i & 2047;
        float v = (k < 640) ? w_ih1[n * 640 + k] : w_hh1[n * 512 + (k - 640)];
        W1f[((size_t)(k >> 3) * 2048 + n) * 8 + (k & 7)] = f2bf(v);
    }
    for (int i = i0; i < 640 * 512; i += stride) {
        int k = i >> 9, n = i & 511;
        float v = (k < 512) ? w_ih2[n * 512 + k] : w_hh2[n * 128 + (k - 512)];
        int d = n & 127, g = n >> 7;
        int t = (g >> 1) * 128 + d, slot = g & 1;
        W2gp[((size_t)k * 256 + t) * 2 + slot] = f2bf(v);
    }
    for (int i = i0; i < 512; i += stride) {
        int d = i & 127, g = i >> 7;
        int t = (g >> 1) * 128 + d, slot = g & 1;
        bias2p[t * 2 + slot] = b_ih2[i] + b_hh2[i];
    }
    for (int i = i0; i < 256 * 1024; i += stride) {
        int k = i >> 10, n = i & 1023;
        float v = (n < VOC) ? w_out[n * 256 + k] : 0.f;
        Woutf[((size_t)(k >> 3) * 1024 + n) * 8 + (k & 7)] = f2bf(v);
    }
    for (int i = i0; i < 2048; i += stride) bias1[i] = b_ih1[i] + b_hh1[i];
    for (int i = i0; i < VOC * H_; i += stride) emb_bf[i] = f2bf(emb[i]);
}

// key [S,B,K] f32 -> key_bf [B,S,K] bf16 ; values likewise
__global__ __launch_bounds__(256) void conv_kv_kernel(
    const float* __restrict__ key, const float* __restrict__ values,
    u16* __restrict__ key_bf, u16* __restrict__ val_bf)
{
    const int i0 = blockIdx.x * 256 + threadIdx.x;
    const int stride = gridDim.x * 256;
    for (int i = i0; i < S_ * B_ * K_; i += stride) {
        int s = i >> 14;
        int r = i & 16383;
        int b = r >> 7, k = r & 127;
        size_t d = ((size_t)b * S_ + s) * K_ + k;
        key_bf[d] = f2bf(key[i]);
        val_bf[d] = f2bf(values[i]);
    }
}

// ---------------- persistent pipelined decoder, 2 barriers/step ----------------
// 128 WGs x 256 threads. WG b: L1 column slice (quarter mh1=b>>5, group hg1=b&31),
// LSTM2 GEMV for row b (h2 WG-local!), attention row b.
// Phase X (ctx(t-1) ready): finish gates1(t) ctx-part -> pointwise -> h1(t);
//                           emb-part of gates1(t+1) into fresh acc1.
// Phase Y (h1(t) ready):    stage h1 quarter -> LDS; gates2(t) GEMV -> h2(t) (LDS);
//                           attention(t) -> ctx(t); h1-part of gates1(t+1).
__global__ __launch_bounds__(256, 1) void decoder_kernel(
    const u16* __restrict__ emb_bf, const int* __restrict__ text,
    const u16* __restrict__ W1f, const float* __restrict__ bias1,
    const u16* __restrict__ W2gp, const float* __restrict__ bias2p,
    const u16* __restrict__ key_bf, const u16* __restrict__ val_bf,
    const int* __restrict__ lens,
    u16* __restrict__ CT, u16* __restrict__ H1,
    u16* __restrict__ Hc, unsigned* __restrict__ bar)
{
    extern __shared__ char smem[];
    u16*   vshare = (u16*)smem;                       // [500][128] bf16, whole kernel
    u16*   h1st   = (u16*)(smem + OFF_H1ST);          // Y: staged h1 [32][516]
    float* Gb     = (float*)(smem + OFF_H1ST);        // X: gate staging [32][65] (aliases h1st)
    float* ebuf   = (float*)(smem + OFF_EBUF);        // Y: gate-exchange / energies / cbuf
    float* h2s    = (float*)(smem + OFF_H2S);         // h2[b] f32, persists across steps
    float* redm   = (float*)(smem + OFF_REDM);        // reductions [16]

    const int wg = blockIdx.x;
    const int tid = threadIdx.x;
    const int lane = tid & 63, wv = tid >> 6;         // wv = wave = gate index (L1 MFMA)
    const int lrow = lane & 15, lk = lane >> 4;

    const int mh1 = wg >> 5, hg1 = wg & 31;           // L1 mapping
    const int n1 = wv * 512 + hg1 * 16 + lrow;        // L1 gate column
    const int b  = wg;                                // attn / LSTM2 batch row
    const int mylen = lens[b];
    const int gd  = tid & 127;                        // GEMV dim
    const int pgo = tid >> 7;                         // 0: gates i,f  1: gates g,o

    float c1r[2] = {0.f, 0.f};                        // LSTM1 cell state
    float c2r = 0.f;                                  // LSTM2 cell state (dim gd, pgo==0)
    f32x4 acc1[2] = {{0,0,0,0},{0,0,0,0}};            // persistent partial gates1

    // ---- init: zero state (sc1), h2s, stage values[b] ----
    {
        int i0 = wg * 256 + tid, stride = NWG * 256;
        for (int i = i0; i < B_ * V_ / 2; i += stride) st_state4(CT + 2 * i, 0u);
        for (int i = i0; i < B_ * H_ / 2; i += stride) st_state4(H1 + 2 * i, 0u);
        if (tid < 128) h2s[tid] = 0.f;
        const u16* vp = val_bf + (size_t)b * S_ * V_;
        for (int i = tid; i < (S_ * V_) / 8; i += 256)
            *reinterpret_cast<short8*>(vshare + i * 8) =
                *reinterpret_cast<const short8*>(vp + (size_t)i * 8);
    }
    gbar(bar, wg);
    // prologue: acc1 = emb-part(0) + h1-part(0) = 0 (emb row0 zeros, h1(-1)=0). ✓

    for (int t = 0; t < NSTEP; ++t) {
        // ================= Phase X =================
        {
            int grow[2];
#pragma unroll
            for (int rt = 0; rt < 2; ++rt) grow[rt] = mh1 * 32 + rt * 16 + lrow;
            // finish gates1(t): ctx-part k[512,640)
#pragma unroll
            for (int kc = 16; kc < 20; ++kc) {
                int k = kc * 32 + lk * 8;
                short8 bw = *reinterpret_cast<const short8*>(W1f + ((size_t)(k >> 3) * 2048 + n1) * 8);
#pragma unroll
                for (int rt = 0; rt < 2; ++rt) {
                    short8 a = ld_state16(CT + grow[rt] * V_ + (k - 512));
                    acc1[rt] = mfma16(a, bw, acc1[rt]);
                }
            }
            float bv = bias1[n1];
#pragma unroll
            for (int rt = 0; rt < 2; ++rt)
#pragma unroll
                for (int j = 0; j < 4; ++j)
                    Gb[(rt * 16 + lk * 4 + j) * 65 + wv * 16 + lrow] = acc1[rt][j] + bv;
            __syncthreads();
            {
                int rb = tid >> 3, j0 = (tid & 7) * 2;
                int bb = mh1 * 32 + rb;
                float gi0 = Gb[rb * 65 + j0],      gf0 = Gb[rb * 65 + 16 + j0];
                float gg0 = Gb[rb * 65 + 32 + j0], go0 = Gb[rb * 65 + 48 + j0];
                float gi1 = Gb[rb * 65 + j0 + 1],      gf1 = Gb[rb * 65 + 16 + j0 + 1];
                float gg1 = Gb[rb * 65 + 32 + j0 + 1], go1 = Gb[rb * 65 + 48 + j0 + 1];
                float cn0 = sigm(gf0) * c1r[0] + sigm(gi0) * tanhf(gg0);
                float cn1 = sigm(gf1) * c1r[1] + sigm(gi1) * tanhf(gg1);
                c1r[0] = cn0; c1r[1] = cn1;
                st_pair(H1 + bb * H_ + hg1 * 16 + j0,
                        sigm(go0) * tanhf(cn0), sigm(go1) * tanhf(cn1));
            }
            // emb-part of gates1(t+1) into fresh acc1 (depends only on text)
            acc1[0] = (f32x4){0,0,0,0}; acc1[1] = (f32x4){0,0,0,0};
            const u16* aemb[2];
#pragma unroll
            for (int rt = 0; rt < 2; ++rt) {
                int tok = text[(t + 1) * B_ + grow[rt]];
                aemb[rt] = emb_bf + (size_t)tok * H_;
            }
#pragma unroll 4
            for (int kc = 0; kc < 16; ++kc) {
                int k = kc * 32 + lk * 8;
                short8 bw = *reinterpret_cast<const short8*>(W1f + ((size_t)(k >> 3) * 2048 + n1) * 8);
#pragma unroll
                for (int rt = 0; rt < 2; ++rt) {
                    short8 a = *reinterpret_cast<const short8*>(aemb[rt] + k);
                    acc1[rt] = mfma16(a, bw, acc1[rt]);
                }
            }
        }
        gbar(bar, wg);

        // ================= Phase Y =================
        {
            // stage h1(t) quarter rows -> LDS
            {
                const u16* src = H1 + (size_t)(mh1 * 32) * H_;
#pragma unroll
                for (int it = 0; it < 8; ++it) {
                    int c = it * 256 + tid;
                    int row = c >> 6, col = (c & 63) * 8;
                    u64 lo = ld_state8(src + (size_t)row * H_ + col);
                    u64 hi = ld_state8(src + (size_t)row * H_ + col + 4);
                    u64* dst = (u64*)(h1st + row * H1ST_STRIDE + col);
                    dst[0] = lo; dst[1] = hi;
                }
            }
            __syncthreads();

            // gates2(t) GEMV: thread covers cols col(t,0), col(t,1); K=640
            float accA = bias2p[tid * 2], accB = bias2p[tid * 2 + 1];
            {
                const u16* h1row = h1st + (b & 31) * H1ST_STRIDE;
#pragma unroll 8
                for (int k = 0; k < 512; k += 2) {
                    unsigned hv = *reinterpret_cast<const unsigned*>(h1row + k);
                    float a0 = bf2f((u16)(hv & 0xffffu));
                    float a1 = bf2f((u16)(hv >> 16));
                    unsigned w0 = *reinterpret_cast<const unsigned*>(W2gp + ((size_t)k * 256 + tid) * 2);
                    unsigned w1 = *reinterpret_cast<const unsigned*>(W2gp + ((size_t)(k + 1) * 256 + tid) * 2);
                    accA += a0 * bf2f((u16)(w0 & 0xffffu));
                    accB += a0 * bf2f((u16)(w0 >> 16));
                    accA += a1 * bf2f((u16)(w1 & 0xffffu));
                    accB += a1 * bf2f((u16)(w1 >> 16));
                }
#pragma unroll 8
                for (int k = 512; k < 640; ++k) {
                    float a = h2s[k - 512];
                    unsigned w = *reinterpret_cast<const unsigned*>(W2gp + ((size_t)k * 256 + tid) * 2);
                    accA += a * bf2f((u16)(w & 0xffffu));
                    accB += a * bf2f((u16)(w >> 16));
                }
            }
            // exchange g,o -> pointwise on i,f threads; h2 stays in LDS
            u16* Hc_t = Hc + (size_t)t * B_ * 256;
            if (pgo) { ebuf[gd] = accA; ebuf[128 + gd] = accB; }
            __syncthreads();
            if (!pgo) {
                float gg = ebuf[gd], go = ebuf[128 + gd];
                float cn = sigm(accB) * c2r + sigm(accA) * tanhf(gg);
                c2r = cn;
                float hn = sigm(go) * tanhf(cn);
                h2s[gd] = hn;
                Hc_t[b * 256 + gd] = f2bf(hn);
            }
            __syncthreads();   // h2s ready; ebuf free for energies

            // attention energies
            for (int s = tid; s < 512; s += 256) {
                float e = -1e9f;
                if (s < S_) {
                    const u16* kp = key_bf + ((size_t)b * S_ + s) * K_;
                    float a = 0.f;
#pragma unroll
                    for (int kk = 0; kk < K_; kk += 8) {
                        short8 kv = *reinterpret_cast<const short8*>(kp + kk);
#pragma unroll
                        for (int j = 0; j < 8; ++j)
                            a += bf2f((u16)kv[j]) * h2s[kk + j];
                    }
                    e = (s < mylen) ? a : -1e9f;
                }
                ebuf[s] = e;
            }
            __syncthreads();

            float m = fmaxf(ebuf[tid], ebuf[tid + 256]);
#pragma unroll
            for (int off = 32; off > 0; off >>= 1) m = fmaxf(m, __shfl_down(m, off));
            if (lane == 0) redm[wv] = m;
            __syncthreads();
            const float maxv = fmaxf(fmaxf(redm[0], redm[1]), fmaxf(redm[2], redm[3]));

            float psum = 0.f;
            for (int s = tid; s < 512; s += 256) {
                float pv = __expf(ebuf[s] - maxv);
                ebuf[s] = pv;
                psum += pv;
            }
#pragma unroll
            for (int off = 32; off > 0; off >>= 1) psum += __shfl_down(psum, off);
            if (lane == 0) redm[4 + wv] = psum;
            __syncthreads();
            const float rinv = 1.f / (redm[4] + redm[5] + redm[6] + redm[7]);

            // context: wave wv owns s in [wv*125, wv*125+125)
            const int s0 = wv * 125;
            float p0 = 0.f, p1 = 0.f;
            for (int s = s0; s < s0 + 125; ++s) {
                float w = ebuf[s];
                unsigned pk = *reinterpret_cast<const unsigned*>(vshare + s * V_ + lane * 2);
                p0 += w * bf2f((u16)(pk & 0xffffu));
                p1 += w * bf2f((u16)(pk >> 16));
            }
            __syncthreads();              // all ebuf (p-values) reads done
            float* cbuf = ebuf;           // alias: dead energies -> ctx partials
            cbuf[wv * V_ + lane * 2]     = p0;
            cbuf[wv * V_ + lane * 2 + 1] = p1;
            __syncthreads();

            if (tid < 64) {
                int v0 = 2 * tid, v1 = 2 * tid + 1;
                float ctx0 = (cbuf[v0] + cbuf[V_ + v0] + cbuf[2 * V_ + v0] + cbuf[3 * V_ + v0]) * rinv;
                float ctx1 = (cbuf[v1] + cbuf[V_ + v1] + cbuf[2 * V_ + v1] + cbuf[3 * V_ + v1]) * rinv;
                st_pair(CT + b * V_ + v0, ctx0, ctx1);
                *reinterpret_cast<unsigned*>(Hc_t + b * 256 + K_ + v0) =
                    (unsigned)f2bf(ctx0) | ((unsigned)f2bf(ctx1) << 16);
            }

            // h1-part of gates1(t+1): k[640,1152) from h1st (intact)
#pragma unroll 4
            for (int kc = 20; kc < 36; ++kc) {
                int k = kc * 32 + lk * 8;
                short8 bw = *reinterpret_cast<const short8*>(W1f + ((size_t)(k >> 3) * 2048 + n1) * 8);
#pragma unroll
                for (int rt = 0; rt < 2; ++rt) {
                    short8 a = *reinterpret_cast<const short8*>(
                        h1st + (rt * 16 + lrow) * H1ST_STRIDE + (kc - 20) * 32 + lk * 8);
                    acc1[rt] = mfma16(a, bw, acc1[rt]);
                }
            }
        }
        gbar(bar, wg);
    }
}

// ---------------- final: pred = Hc[31872,256] @ Wout^T + b_out ----------------
__global__ __launch_bounds__(256) void k4_kernel(
    const u16* __restrict__ Hc, const u16* __restrict__ Woutf,
    const float* __restrict__ b_out, float* __restrict__ out)
{
    const int bx = blockIdx.x;
    const int mt = bx >> 4, nt = bx & 15;
    const int tid = threadIdx.x;
    const int lane = tid & 63, g = tid >> 6;
    const int lrow = lane & 15, lk = lane >> 4;
    const int n = nt * 64 + g * 16 + lrow;
    const float bias = (n < VOC) ? b_out[n] : 0.f;

    f32x4 acc[8];
#pragma unroll
    for (int rt = 0; rt < 8; ++rt) acc[rt] = (f32x4){bias, bias, bias, bias};

#pragma unroll
    for (int kc = 0; kc < 8; ++kc) {
        int k = kc * 32 + lk * 8;
        short8 bw = *reinterpret_cast<const short8*>(Woutf + ((size_t)(k >> 3) * 1024 + n) * 8);
#pragma unroll
        for (int rt = 0; rt < 8; ++rt) {
            int R = mt * 128 + rt * 16 + lrow;
            short8 a = *reinterpret_cast<const short8*>(Hc + (size_t)R * 256 + k);
            acc[rt] = mfma16(a, bw, acc[rt]);
        }
    }
    if (n < VOC) {
#pragma unroll
        for (int rt = 0; rt < 8; ++rt)
#pragma unroll
            for (int j = 0; j < 4; ++j) {
                int R = mt * 128 + rt * 16 + lk * 4 + j;
                int tt = R >> 7, bb = R & 127;
                out[((size_t)bb * NSTEP + tt) * VOC + n] = acc[rt][j];
            }
    }
}

// ---------------- host ----------------
extern "C" void kernel_launch(void* const* d_in, const int* in_sizes, int n_in,
                              void* d_out, int out_size, void* d_ws, size_t ws_size,
                              hipStream_t stream)
{
    const float* key    = (const float*)d_in[0];
    const float* values = (const float*)d_in[1];
    const int*   lens   = (const int*)d_in[2];
    const int*   text   = (const int*)d_in[3];
    const float* emb    = (const float*)d_in[4];
    const float* w_ih1  = (const float*)d_in[5];
    const float* w_hh1  = (const float*)d_in[6];
    const float* b_ih1  = (const float*)d_in[7];
    const float* b_hh1  = (const float*)d_in[8];
    const float* w_ih2  = (const float*)d_in[9];
    const float* w_hh2  = (const float*)d_in[10];
    const float* b_ih2  = (const float*)d_in[11];
    const float* b_hh2  = (const float*)d_in[12];
    const float* w_out  = (const float*)d_in[13];
    const float* b_out  = (const float*)d_in[14];

    char* p = (char*)d_ws;
    auto alloc = [&](size_t bytes) -> char* {
        char* r = p;
        p += (bytes + 255) & ~(size_t)255;
        return r;
    };
    u16*      key_bf = (u16*)     alloc((size_t)B_ * S_ * K_ * 2);
    u16*      val_bf = (u16*)     alloc((size_t)B_ * S_ * V_ * 2);
    u16*      emb_bf = (u16*)     alloc((size_t)VOC * H_ * 2);
    u16*      W1f    = (u16*)     alloc((size_t)1152 * 2048 * 2);
    u16*      W2gp   = (u16*)     alloc((size_t)640 * 512 * 2);
    u16*      Woutf  = (u16*)     alloc((size_t)256 * 1024 * 2);
    float*    bias1  = (float*)   alloc(2048 * 4);
    float*    bias2p = (float*)   alloc(512 * 4);
    u16*      CT     = (u16*)     alloc((size_t)B_ * V_ * 2);
    u16*      H1     = (u16*)     alloc((size_t)B_ * H_ * 2);
    u16*      Hc     = (u16*)     alloc((size_t)NSTEP * B_ * 256 * 2);
    unsigned* bar    = (unsigned*)alloc(4096);
    (void)ws_size; (void)in_sizes; (void)n_in; (void)out_size;

    hipFuncSetAttribute((const void*)decoder_kernel,
                        hipFuncAttributeMaxDynamicSharedMemorySize, SMEM_BYTES);

    pack_kernel<<<512, 256, 0, stream>>>(w_ih1, w_hh1, b_ih1, b_hh1,
                                         w_ih2, w_hh2, b_ih2, b_hh2,
                                         w_out, emb, W1f, W2gp, Woutf, bias1, bias2p, emb_bf,
                                         bar);
    conv_kv_kernel<<<4096, 256, 0, stream>>>(key, values, key_bf, val_bf);

    decoder_kernel<<<NWG, 256, SMEM_BYTES, stream>>>(emb_bf, text, W1f, bias1, W2gp, bias2p,
                                                     key_bf, val_bf, lens, CT, H1, Hc, bar);

    k4_kernel<<<NSTEP * 16, 256, 0, stream>>>(Hc, Woutf, b_out, (float*)d_out);
}

// Round 8
// 7661.014 us; speedup vs baseline: 2.2800x; 2.2800x over previous
//
#include <hip/hip_runtime.h>
#include <hip/hip_bf16.h>

typedef unsigned short u16;
typedef unsigned long long u64;
typedef short short8 __attribute__((ext_vector_type(8)));
typedef float f32x4 __attribute__((ext_vector_type(4)));

#define S_ 500
#define B_ 128
#define T_ 250
#define H_ 512
#define K_ 128
#define V_ 128
#define VOC 1000
#define NSTEP 249   // T-1
#define NWG 160     // 128 row-WGs + 32 L2-WGs
#define NROW 128

#define VSH_BYTES   128000          // values[b]: 500*128*2
#define H1ST_STRIDE 520             // padded row stride (shorts) for staged h1
#define ALIAS_BYTES 33280           // 32*520*2
#define SMEM_BYTES  (VSH_BYTES + ALIAS_BYTES)   // 161280 <= 163840

__device__ __forceinline__ float bf2f(u16 u) {
    union { unsigned int i; float f; } x; x.i = ((unsigned int)u) << 16; return x.f;
}
__device__ __forceinline__ u16 f2bf(float f) {
    union { float f; unsigned int i; } x; x.f = f;
    unsigned int r = x.i + 0x7fffu + ((x.i >> 16) & 1u);
    return (u16)(r >> 16);
}
__device__ __forceinline__ float sigm(float x) { return 1.f / (1.f + __expf(-x)); }
__device__ __forceinline__ float tanh_f(float x) { return 2.f / (1.f + __expf(-2.f * x)) - 1.f; }
__device__ __forceinline__ f32x4 mfma16(short8 a, short8 b, f32x4 c) {
    return __builtin_amdgcn_mfma_f32_16x16x32_bf16(a, b, c, 0, 0, 0);
}

// ---- agent-scope coherent (sc1, MALL-direct) state accessors, NO fences ----
__device__ __forceinline__ u64 ld_state8(const u16* p) {
    return __hip_atomic_load((const u64*)p, __ATOMIC_RELAXED, __HIP_MEMORY_SCOPE_AGENT);
}
__device__ __forceinline__ short8 ld_state16(const u16* p) {
    union { u64 q[2]; short8 s; } u;
    u.q[0] = ld_state8(p); u.q[1] = ld_state8(p + 4);
    return u.s;
}
__device__ __forceinline__ unsigned ld_state4(const u16* p) {
    return __hip_atomic_load((const unsigned*)p, __ATOMIC_RELAXED, __HIP_MEMORY_SCOPE_AGENT);
}
__device__ __forceinline__ void st_state4(u16* p, unsigned v) {
    __hip_atomic_store((unsigned*)p, v, __ATOMIC_RELAXED, __HIP_MEMORY_SCOPE_AGENT);
}
__device__ __forceinline__ void st_pair(u16* p, float a, float b) {
    st_state4(p, (unsigned)f2bf(a) | ((unsigned)f2bf(b) << 16));
}

// Device-scope FLAG-ARRAY barrier, all relaxed sc1 (no buffer_inv, no RMW
// serialization). Arrival: one parallel store flags[wg]=tag. Detection: thread i
// polls flags[i] until >= tag (tags monotone, no reset; later tags satisfy
// earlier waiters). Visibility: __syncthreads drains vmcnt (data stores MALL-acked)
// before the flag store; readers see flag at MALL then read data at MALL.
__device__ __forceinline__ void gbar(unsigned* flags, int wg, unsigned tag) {
    __syncthreads();
    if (threadIdx.x == 0)
        __hip_atomic_store(flags + wg, tag, __ATOMIC_RELAXED, __HIP_MEMORY_SCOPE_AGENT);
    if (threadIdx.x < NWG) {
        while (__hip_atomic_load(flags + threadIdx.x, __ATOMIC_RELAXED,
                                 __HIP_MEMORY_SCOPE_AGENT) < tag) {}
    }
    __syncthreads();
}

// ---------------- setup: pack weights into fragment-friendly bf16 layouts ----------------
__global__ __launch_bounds__(256) void pack_kernel(
    const float* __restrict__ w_ih1, const float* __restrict__ w_hh1,
    const float* __restrict__ b_ih1, const float* __restrict__ b_hh1,
    const float* __restrict__ w_ih2, const float* __restrict__ w_hh2,
    const float* __restrict__ b_ih2, const float* __restrict__ b_hh2,
    const float* __restrict__ w_out, const float* __restrict__ emb,
    u16* __restrict__ W1f, u16* __restrict__ W2f, u16* __restrict__ Woutf,
    float* __restrict__ bias1, float* __restrict__ bias2, u16* __restrict__ emb_bf,
    unsigned* __restrict__ bar)
{
    const int i0 = blockIdx.x * 256 + threadIdx.x;
    const int stride = gridDim.x * 256;
    for (int i = i0; i < 1024; i += stride)
        __hip_atomic_store(bar + i, 0u, __ATOMIC_RELAXED, __HIP_MEMORY_SCOPE_AGENT);
    for (int i = i0; i < 1152 * 2048; i += stride) {
        int k = i >> 11, n = i & 2047;
        float v = (k < 640) ? w_ih1[n * 640 + k] : w_hh1[n * 512 + (k - 640)];
        W1f[((size_t)(k >> 3) * 2048 + n) * 8 + (k & 7)] = f2bf(v);
    }
    for (int i = i0; i < 640 * 512; i += stride) {
        int k = i >> 9, n = i & 511;
        float v = (k < 512) ? w_ih2[n * 512 + k] : w_hh2[n * 128 + (k - 512)];
        W2f[((size_t)(k >> 3) * 512 + n) * 8 + (k & 7)] = f2bf(v);
    }
    for (int i = i0; i < 256 * 1024; i += stride) {
        int k = i >> 10, n = i & 1023;
        float v = (n < VOC) ? w_out[n * 256 + k] : 0.f;
        Woutf[((size_t)(k >> 3) * 1024 + n) * 8 + (k & 7)] = f2bf(v);
    }
    for (int i = i0; i < 2048; i += stride) bias1[i] = b_ih1[i] + b_hh1[i];
    for (int i = i0; i < 512; i += stride) bias2[i] = b_ih2[i] + b_hh2[i];
    for (int i = i0; i < VOC * H_; i += stride) emb_bf[i] = f2bf(emb[i]);
}

// key [S,B,K] f32 -> key_bf [B,S,K] bf16 ; values likewise
__global__ __launch_bounds__(256) void conv_kv_kernel(
    const float* __restrict__ key, const float* __restrict__ values,
    u16* __restrict__ key_bf, u16* __restrict__ val_bf)
{
    const int i0 = blockIdx.x * 256 + threadIdx.x;
    const int stride = gridDim.x * 256;
    for (int i = i0; i < S_ * B_ * K_; i += stride) {
        int s = i >> 14;
        int r = i & 16383;
        int b = r >> 7, k = r & 127;
        size_t d = ((size_t)b * S_ + s) * K_ + k;
        key_bf[d] = f2bf(key[i]);
        val_bf[d] = f2bf(values[i]);
    }
}

// ---------------- persistent pipelined decoder (round-6 structure) ----------------
// 160 WGs x 256 threads. wg<128 "row-WG" (L1 col-slice + attention row b=wg);
// wg>=128 "L2-WG" (LSTM2 GEMM tile). Per step:
//   P_A row: finish gates1(t) (ctx K=128) + pointwise -> h1(t)
//   P_B row: partial gates1(t+1) (emb+h1, K=1024) || L2: finish gates2(t) -> h2(t)
//   P_C row: attention(t) -> ctx(t), Hc           || L2: partial gates2(t+1) (h2 K=128)
__global__ __launch_bounds__(256, 1) void decoder_kernel(
    const u16* __restrict__ emb_bf, const int* __restrict__ text,
    const u16* __restrict__ W1f, const float* __restrict__ bias1,
    const u16* __restrict__ W2f, const float* __restrict__ bias2,
    const u16* __restrict__ key_bf, const u16* __restrict__ val_bf,
    const int* __restrict__ lens,
    u16* __restrict__ CT, u16* __restrict__ H1, u16* __restrict__ H2,
    u16* __restrict__ Hc, unsigned* __restrict__ bar)
{
    extern __shared__ char smem[];
    u16*   vshare = (u16*)smem;                     // [500][128] bf16 (row-WGs only)
    char*  alias  = smem + VSH_BYTES;               // phase-disjoint union:
    u16*   h1st   = (u16*)alias;                    //   P_B: staged h1 [32][520]
    float* Gb     = (float*)alias;                  //   P_A / L2-P_B: gates [32][65]
    float* ebuf   = (float*)alias;                  //   P_C: energies [512]
    float* cbuf   = (float*)(alias + 2048);         //   P_C: ctx partials [4][128]
    float* h2s    = (float*)(alias + 4096);         //   P_C: query [128]
    float* redm   = (float*)(alias + 4608);         //   P_C: reductions [16]

    const int wg = blockIdx.x;
    const int tid = threadIdx.x;
    const int lane = tid & 63, wv = tid >> 6;       // wv = wave = gate index
    const int lrow = lane & 15, lk = lane >> 4;
    const bool isrow = wg < NROW;

    const int mh1 = wg >> 5, hg1 = wg & 31;         // row-WG L1 mapping
    const int n1 = wv * 512 + hg1 * 16 + lrow;
    const int l2 = wg - NROW;
    const int q2 = l2 >> 3, hg2 = l2 & 7;           // L2-WG mapping
    const int n2 = wv * 128 + hg2 * 16 + lrow;
    const int b  = wg;                              // attn batch row (row-WGs)
    const int mylen = isrow ? lens[b] : 0;

    float c1r[2] = {0.f, 0.f};                      // LSTM1 cell state
    float c2r[2] = {0.f, 0.f};                      // LSTM2 cell state
    f32x4 acc1[2] = {{0,0,0,0},{0,0,0,0}};          // partial gates1 (persistent)
    f32x4 acc2[2] = {{0,0,0,0},{0,0,0,0}};          // partial gates2 (persistent)
    unsigned tag = 1;                               // barrier tag (monotone)

    // ---- init: zero state (sc1); row-WGs stage values[b] into LDS ----
    {
        int i0 = wg * 256 + tid, stride = NWG * 256;
        for (int i = i0; i < B_ * V_ / 2; i += stride) st_state4(CT + 2 * i, 0u);
        for (int i = i0; i < B_ * H_ / 2; i += stride) st_state4(H1 + 2 * i, 0u);
        for (int i = i0; i < B_ * K_;     i += stride) st_state4(H2 + 2 * i, 0u); // both bufs
        if (isrow) {
            const u16* vp = val_bf + (size_t)b * S_ * V_;
            for (int i = tid; i < (S_ * V_) / 8; i += 256)
                *reinterpret_cast<short8*>(vshare + i * 8) =
                    *reinterpret_cast<const short8*>(vp + (size_t)i * 8);
        }
    }
    gbar(bar, wg, tag++);
    // prologue partials are exactly 0: emb row0 zeros, h1(-1)=h2(-1)=0.

    for (int t = 0; t < NSTEP; ++t) {
        const int nxt = (t & 1) ^ 1;
        u16* H2n = H2 + (size_t)nxt * B_ * K_;

        // ======== P_A: row-WGs finish gates1(t) + LSTM1 pointwise ========
        if (isrow) {
            int grow[2];
#pragma unroll
            for (int rt = 0; rt < 2; ++rt) grow[rt] = mh1 * 32 + rt * 16 + lrow;
            // ctx-part k[512,640)
#pragma unroll
            for (int kc = 16; kc < 20; ++kc) {
                int k = kc * 32 + lk * 8;
                short8 bw = *reinterpret_cast<const short8*>(W1f + ((size_t)(k >> 3) * 2048 + n1) * 8);
#pragma unroll
                for (int rt = 0; rt < 2; ++rt) {
                    short8 a = ld_state16(CT + grow[rt] * V_ + (k - 512));
                    acc1[rt] = mfma16(a, bw, acc1[rt]);
                }
            }
            float bv = bias1[n1];
#pragma unroll
            for (int rt = 0; rt < 2; ++rt)
#pragma unroll
                for (int j = 0; j < 4; ++j)
                    Gb[(rt * 16 + lk * 4 + j) * 65 + wv * 16 + lrow] = acc1[rt][j] + bv;
            __syncthreads();
            {
                int rb = tid >> 3, j0 = (tid & 7) * 2;
                int bb = mh1 * 32 + rb;
                float gi0 = Gb[rb * 65 + j0],      gf0 = Gb[rb * 65 + 16 + j0];
                float gg0 = Gb[rb * 65 + 32 + j0], go0 = Gb[rb * 65 + 48 + j0];
                float gi1 = Gb[rb * 65 + j0 + 1],      gf1 = Gb[rb * 65 + 16 + j0 + 1];
                float gg1 = Gb[rb * 65 + 32 + j0 + 1], go1 = Gb[rb * 65 + 48 + j0 + 1];
                float cn0 = sigm(gf0) * c1r[0] + sigm(gi0) * tanh_f(gg0);
                float cn1 = sigm(gf1) * c1r[1] + sigm(gi1) * tanh_f(gg1);
                c1r[0] = cn0; c1r[1] = cn1;
                st_pair(H1 + bb * H_ + hg1 * 16 + j0,
                        sigm(go0) * tanh_f(cn0), sigm(go1) * tanh_f(cn1));
            }
        }
        gbar(bar, wg, tag++);

        // ======== P_B: row-WGs partial gates1(t+1)  ||  L2-WGs finish gates2(t) ========
        if (isrow) {
            // stage h1(t) rows [mh1*32, +32) -> LDS
            {
                const u16* src = H1 + (size_t)(mh1 * 32) * H_;
#pragma unroll
                for (int it = 0; it < 8; ++it) {
                    int c = it * 256 + tid;
                    int row = c >> 6, col = (c & 63) * 8;
                    u64 lo = ld_state8(src + (size_t)row * H_ + col);
                    u64 hi = ld_state8(src + (size_t)row * H_ + col + 4);
                    u64* dst = (u64*)(h1st + row * H1ST_STRIDE + col);
                    dst[0] = lo; dst[1] = hi;
                }
            }
            const u16* aemb[2];
#pragma unroll
            for (int rt = 0; rt < 2; ++rt) {
                int grow = mh1 * 32 + rt * 16 + lrow;
                int tok = text[(t + 1) * B_ + grow];
                aemb[rt] = emb_bf + (size_t)tok * H_;
            }
            __syncthreads();
            acc1[0] = (f32x4){0,0,0,0}; acc1[1] = (f32x4){0,0,0,0};
            // emb-part k[0,512)
#pragma unroll 4
            for (int kc = 0; kc < 16; ++kc) {
                int k = kc * 32 + lk * 8;
                short8 bw = *reinterpret_cast<const short8*>(W1f + ((size_t)(k >> 3) * 2048 + n1) * 8);
#pragma unroll
                for (int rt = 0; rt < 2; ++rt) {
                    short8 a = *reinterpret_cast<const short8*>(aemb[rt] + k);
                    acc1[rt] = mfma16(a, bw, acc1[rt]);
                }
            }
            // h1-part k[640,1152) from LDS stage
#pragma unroll 4
            for (int kc = 20; kc < 36; ++kc) {
                int k = kc * 32 + lk * 8;
                short8 bw = *reinterpret_cast<const short8*>(W1f + ((size_t)(k >> 3) * 2048 + n1) * 8);
#pragma unroll
                for (int rt = 0; rt < 2; ++rt) {
                    short8 a = *reinterpret_cast<const short8*>(
                        h1st + (rt * 16 + lrow) * H1ST_STRIDE + (kc - 20) * 32 + lk * 8);
                    acc1[rt] = mfma16(a, bw, acc1[rt]);
                }
            }
        } else {
            // stage h1(t) rows [q2*32, +32) -> LDS
            {
                const u16* src = H1 + (size_t)(q2 * 32) * H_;
#pragma unroll
                for (int it = 0; it < 8; ++it) {
                    int c = it * 256 + tid;
                    int row = c >> 6, col = (c & 63) * 8;
                    u64 lo = ld_state8(src + (size_t)row * H_ + col);
                    u64 hi = ld_state8(src + (size_t)row * H_ + col + 4);
                    u64* dst = (u64*)(h1st + row * H1ST_STRIDE + col);
                    dst[0] = lo; dst[1] = hi;
                }
            }
            __syncthreads();
            // h1-part k[0,512) into persistent acc2 (h2-part already there)
#pragma unroll 4
            for (int kc = 0; kc < 16; ++kc) {
                int k = kc * 32 + lk * 8;
                short8 bw = *reinterpret_cast<const short8*>(W2f + ((size_t)(k >> 3) * 512 + n2) * 8);
#pragma unroll
                for (int rt = 0; rt < 2; ++rt) {
                    short8 a = *reinterpret_cast<const short8*>(
                        h1st + (rt * 16 + lrow) * H1ST_STRIDE + kc * 32 + lk * 8);
                    acc2[rt] = mfma16(a, bw, acc2[rt]);
                }
            }
            float bv = bias2[n2];
            __syncthreads();   // h1st reads done; Gb may overwrite alias
#pragma unroll
            for (int rt = 0; rt < 2; ++rt)
#pragma unroll
                for (int j = 0; j < 4; ++j)
                    Gb[(rt * 16 + lk * 4 + j) * 65 + wv * 16 + lrow] = acc2[rt][j] + bv;
            __syncthreads();
            {
                int rb = tid >> 3, j0 = (tid & 7) * 2;
                int bb = q2 * 32 + rb;
                float gi0 = Gb[rb * 65 + j0],      gf0 = Gb[rb * 65 + 16 + j0];
                float gg0 = Gb[rb * 65 + 32 + j0], go0 = Gb[rb * 65 + 48 + j0];
                float gi1 = Gb[rb * 65 + j0 + 1],      gf1 = Gb[rb * 65 + 16 + j0 + 1];
                float gg1 = Gb[rb * 65 + 32 + j0 + 1], go1 = Gb[rb * 65 + 48 + j0 + 1];
                float cn0 = sigm(gf0) * c2r[0] + sigm(gi0) * tanh_f(gg0);
                float cn1 = sigm(gf1) * c2r[1] + sigm(gi1) * tanh_f(gg1);
                c2r[0] = cn0; c2r[1] = cn1;
                st_pair(H2n + bb * K_ + hg2 * 16 + j0,
                        sigm(go0) * tanh_f(cn0), sigm(go1) * tanh_f(cn1));
            }
        }
        gbar(bar, wg, tag++);

        // ======== P_C: row-WGs attention(t)  ||  L2-WGs partial gates2(t+1) ========
        if (isrow) {
            u16* Hc_t = Hc + (size_t)t * B_ * 256;
            if (tid < 64) {
                unsigned v = ld_state4(H2n + b * K_ + 2 * tid);
                h2s[2 * tid]     = bf2f((u16)(v & 0xffffu));
                h2s[2 * tid + 1] = bf2f((u16)(v >> 16));
                *reinterpret_cast<unsigned*>(Hc_t + b * 256 + 2 * tid) = v;
            }
            __syncthreads();

            for (int s = tid; s < 512; s += 256) {
                float e = -1e9f;
                if (s < S_) {
                    const u16* kp = key_bf + ((size_t)b * S_ + s) * K_;
                    float a = 0.f;
#pragma unroll
                    for (int kk = 0; kk < K_; kk += 8) {
                        short8 kv = *reinterpret_cast<const short8*>(kp + kk);
#pragma unroll
                        for (int j = 0; j < 8; ++j)
                            a += bf2f((u16)kv[j]) * h2s[kk + j];
                    }
                    e = (s < mylen) ? a : -1e9f;
                }
                ebuf[s] = e;
            }
            __syncthreads();

            float m = fmaxf(ebuf[tid], ebuf[tid + 256]);
#pragma unroll
            for (int off = 32; off > 0; off >>= 1) m = fmaxf(m, __shfl_down(m, off));
            if (lane == 0) redm[wv] = m;
            __syncthreads();
            const float maxv = fmaxf(fmaxf(redm[0], redm[1]), fmaxf(redm[2], redm[3]));

            float psum = 0.f;
            for (int s = tid; s < 512; s += 256) {
                float pv = __expf(ebuf[s] - maxv);
                ebuf[s] = pv;
                psum += pv;
            }
#pragma unroll
            for (int off = 32; off > 0; off >>= 1) psum += __shfl_down(psum, off);
            if (lane == 0) redm[4 + wv] = psum;
            __syncthreads();
            const float rinv = 1.f / (redm[4] + redm[5] + redm[6] + redm[7]);

            const int s0 = wv * 125;
            float p0 = 0.f, p1 = 0.f;
            for (int s = s0; s < s0 + 125; ++s) {
                float w = ebuf[s];
                unsigned pk = *reinterpret_cast<const unsigned*>(vshare + s * V_ + lane * 2);
                p0 += w * bf2f((u16)(pk & 0xffffu));
                p1 += w * bf2f((u16)(pk >> 16));
            }
            cbuf[wv * V_ + lane * 2]     = p0;
            cbuf[wv * V_ + lane * 2 + 1] = p1;
            __syncthreads();

            if (tid < 64) {
                int v0 = 2 * tid, v1 = 2 * tid + 1;
                float ctx0 = (cbuf[v0] + cbuf[V_ + v0] + cbuf[2 * V_ + v0] + cbuf[3 * V_ + v0]) * rinv;
                float ctx1 = (cbuf[v1] + cbuf[V_ + v1] + cbuf[2 * V_ + v1] + cbuf[3 * V_ + v1]) * rinv;
                st_pair(CT + b * V_ + v0, ctx0, ctx1);
                *reinterpret_cast<unsigned*>(Hc_t + b * 256 + K_ + v0) =
                    (unsigned)f2bf(ctx0) | ((unsigned)f2bf(ctx1) << 16);
            }
        } else {
            // partial gates2(t+1): h2(t)-part k[512,640)
            acc2[0] = (f32x4){0,0,0,0}; acc2[1] = (f32x4){0,0,0,0};
#pragma unroll
            for (int kc = 16; kc < 20; ++kc) {
                int k = kc * 32 + lk * 8;
                short8 bw = *reinterpret_cast<const short8*>(W2f + ((size_t)(k >> 3) * 512 + n2) * 8);
#pragma unroll
                for (int rt = 0; rt < 2; ++rt) {
                    short8 a = ld_state16(H2n + (q2 * 32 + rt * 16 + lrow) * K_ + (k - 512));
                    acc2[rt] = mfma16(a, bw, acc2[rt]);
                }
            }
        }
        gbar(bar, wg, tag++);
    }
}

// ---------------- final: pred = Hc[31872,256] @ Wout^T + b_out ----------------
__global__ __launch_bounds__(256) void k4_kernel(
    const u16* __restrict__ Hc, const u16* __restrict__ Woutf,
    const float* __restrict__ b_out, float* __restrict__ out)
{
    const int bx = blockIdx.x;
    const int mt = bx >> 4, nt = bx & 15;
    const int tid = threadIdx.x;
    const int lane = tid & 63, g = tid >> 6;
    const int lrow = lane & 15, lk = lane >> 4;
    const int n = nt * 64 + g * 16 + lrow;
    const float bias = (n < VOC) ? b_out[n] : 0.f;

    f32x4 acc[8];
#pragma unroll
    for (int rt = 0; rt < 8; ++rt) acc[rt] = (f32x4){bias, bias, bias, bias};

#pragma unroll
    for (int kc = 0; kc < 8; ++kc) {
        int k = kc * 32 + lk * 8;
        short8 bw = *reinterpret_cast<const short8*>(Woutf + ((size_t)(k >> 3) * 1024 + n) * 8);
#pragma unroll
        for (int rt = 0; rt < 8; ++rt) {
            int R = mt * 128 + rt * 16 + lrow;
            short8 a = *reinterpret_cast<const short8*>(Hc + (size_t)R * 256 + k);
            acc[rt] = mfma16(a, bw, acc[rt]);
        }
    }
    if (n < VOC) {
#pragma unroll
        for (int rt = 0; rt < 8; ++rt)
#pragma unroll
            for (int j = 0; j < 4; ++j) {
                int R = mt * 128 + rt * 16 + lk * 4 + j;
                int tt = R >> 7, bb = R & 127;
                out[((size_t)bb * NSTEP + tt) * VOC + n] = acc[rt][j];
            }
    }
}

// ---------------- host ----------------
extern "C" void kernel_launch(void* const* d_in, const int* in_sizes, int n_in,
                              void* d_out, int out_size, void* d_ws, size_t ws_size,
                              hipStream_t stream)
{
    const float* key    = (const float*)d_in[0];
    const float* values = (const float*)d_in[1];
    const int*   lens   = (const int*)d_in[2];
    const int*   text   = (const int*)d_in[3];
    const float* emb    = (const float*)d_in[4];
    const float* w_ih1  = (const float*)d_in[5];
    const float* w_hh1  = (const float*)d_in[6];
    const float* b_ih1  = (const float*)d_in[7];
    const float* b_hh1  = (const float*)d_in[8];
    const float* w_ih2  = (const float*)d_in[9];
    const float* w_hh2  = (const float*)d_in[10];
    const float* b_ih2  = (const float*)d_in[11];
    const float* b_hh2  = (const float*)d_in[12];
    const float* w_out  = (const float*)d_in[13];
    const float* b_out  = (const float*)d_in[14];

    char* p = (char*)d_ws;
    auto alloc = [&](size_t bytes) -> char* {
        char* r = p;
        p += (bytes + 255) & ~(size_t)255;
        return r;
    };
    u16*      key_bf = (u16*)     alloc((size_t)B_ * S_ * K_ * 2);
    u16*      val_bf = (u16*)     alloc((size_t)B_ * S_ * V_ * 2);
    u16*      emb_bf = (u16*)     alloc((size_t)VOC * H_ * 2);
    u16*      W1f    = (u16*)     alloc((size_t)1152 * 2048 * 2);
    u16*      W2f    = (u16*)     alloc((size_t)640 * 512 * 2);
    u16*      Woutf  = (u16*)     alloc((size_t)256 * 1024 * 2);
    float*    bias1  = (float*)   alloc(2048 * 4);
    float*    bias2  = (float*)   alloc(512 * 4);
    u16*      CT     = (u16*)     alloc((size_t)B_ * V_ * 2);       // single buffer
    u16*      H1     = (u16*)     alloc((size_t)B_ * H_ * 2);       // single buffer
    u16*      H2     = (u16*)     alloc((size_t)2 * B_ * K_ * 2);   // ping-pong
    u16*      Hc     = (u16*)     alloc((size_t)NSTEP * B_ * 256 * 2);
    unsigned* bar    = (unsigned*)alloc(4096);
    (void)ws_size; (void)in_sizes; (void)n_in; (void)out_size;

    hipFuncSetAttribute((const void*)decoder_kernel,
                        hipFuncAttributeMaxDynamicSharedMemorySize, SMEM_BYTES);

    pack_kernel<<<512, 256, 0, stream>>>(w_ih1, w_hh1, b_ih1, b_hh1,
                                         w_ih2, w_hh2, b_ih2, b_hh2,
                                         w_out, emb, W1f, W2f, Woutf, bias1, bias2, emb_bf,
                                         bar);
    conv_kv_kernel<<<4096, 256, 0, stream>>>(key, values, key_bf, val_bf);

    decoder_kernel<<<NWG, 256, SMEM_BYTES, stream>>>(emb_bf, text, W1f, bias1, W2f, bias2,
                                                     key_bf, val_bf, lens, CT, H1, H2, Hc, bar);

    k4_kernel<<<NSTEP * 16, 256, 0, stream>>>(Hc, Woutf, b_out, (float*)d_out);
}

// Round 9
// 5369.394 us; speedup vs baseline: 3.2531x; 1.4268x over previous
//
#include <hip/hip_runtime.h>
#include <hip/hip_bf16.h>

typedef unsigned short u16;
typedef unsigned long long u64;
typedef short short8 __attribute__((ext_vector_type(8)));
typedef float f32x4 __attribute__((ext_vector_type(4)));

#define S_ 500
#define B_ 128
#define T_ 250
#define H_ 512
#define K_ 128
#define V_ 128
#define VOC 1000
#define NSTEP 249   // T-1
#define NWG 160     // 128 row-WGs + 32 L2-WGs
#define NROW 128

#define VSH_BYTES   128000          // values[b]: 500*128*2
#define H1ST_STRIDE 520             // padded row stride (shorts) for staged h1
#define ALIAS_BYTES 33280           // 32*520*2
#define SMEM_BYTES  (VSH_BYTES + ALIAS_BYTES)   // 161280 <= 163840

// flag regions (u32 indices into bar)
#define FA    0     // [128] h1(t) ready, per row-WG
#define FB    128   // [32]  h2(t) ready, per L2-WG
#define FC    192   // [128] ctx(t) ready, per row-WG
#define FINIT 384   // [160] init done

__device__ __forceinline__ float bf2f(u16 u) {
    union { unsigned int i; float f; } x; x.i = ((unsigned int)u) << 16; return x.f;
}
__device__ __forceinline__ u16 f2bf(float f) {
    union { float f; unsigned int i; } x; x.f = f;
    unsigned int r = x.i + 0x7fffu + ((x.i >> 16) & 1u);
    return (u16)(r >> 16);
}
__device__ __forceinline__ float sigm(float x) { return 1.f / (1.f + __expf(-x)); }
__device__ __forceinline__ float tanh_f(float x) { return 2.f / (1.f + __expf(-2.f * x)) - 1.f; }
__device__ __forceinline__ f32x4 mfma16(short8 a, short8 b, f32x4 c) {
    return __builtin_amdgcn_mfma_f32_16x16x32_bf16(a, b, c, 0, 0, 0);
}

// ---- agent-scope coherent (sc1, MALL-direct) state accessors, NO fences ----
__device__ __forceinline__ u64 ld_state8(const u16* p) {
    return __hip_atomic_load((const u64*)p, __ATOMIC_RELAXED, __HIP_MEMORY_SCOPE_AGENT);
}
__device__ __forceinline__ short8 ld_state16(const u16* p) {
    union { u64 q[2]; short8 s; } u;
    u.q[0] = ld_state8(p); u.q[1] = ld_state8(p + 4);
    return u.s;
}
__device__ __forceinline__ unsigned ld_state4(const u16* p) {
    return __hip_atomic_load((const unsigned*)p, __ATOMIC_RELAXED, __HIP_MEMORY_SCOPE_AGENT);
}
__device__ __forceinline__ void st_state4(u16* p, unsigned v) {
    __hip_atomic_store((unsigned*)p, v, __ATOMIC_RELAXED, __HIP_MEMORY_SCOPE_AGENT);
}
__device__ __forceinline__ void st_pair(u16* p, float a, float b) {
    st_state4(p, (unsigned)f2bf(a) | ((unsigned)f2bf(b) << 16));
}

// ---- point-to-point flags (monotone tags, no reset, all relaxed sc1) ----
// Producer: __syncthreads drains vmcnt (data stores MALL-acked), then one store.
// Consumer: n threads poll n producer flags (with s_sleep backoff), then
// __syncthreads releases the WG; data then read at MALL (sc1) => fresh.
__device__ __forceinline__ void set_flag(unsigned* f, unsigned tag) {
    __syncthreads();
    if (threadIdx.x == 0)
        __hip_atomic_store(f, tag, __ATOMIC_RELAXED, __HIP_MEMORY_SCOPE_AGENT);
}
__device__ __forceinline__ void wait_flags(const unsigned* f, int n, unsigned tag) {
    if ((int)threadIdx.x < n) {
        while (__hip_atomic_load(f + threadIdx.x, __ATOMIC_RELAXED,
                                 __HIP_MEMORY_SCOPE_AGENT) < tag)
            __builtin_amdgcn_s_sleep(1);
    }
    __syncthreads();
}

// ---------------- setup: pack weights into fragment-friendly bf16 layouts ----------------
__global__ __launch_bounds__(256) void pack_kernel(
    const float* __restrict__ w_ih1, const float* __restrict__ w_hh1,
    const float* __restrict__ b_ih1, const float* __restrict__ b_hh1,
    const float* __restrict__ w_ih2, const float* __restrict__ w_hh2,
    const float* __restrict__ b_ih2, const float* __restrict__ b_hh2,
    const float* __restrict__ w_out, const float* __restrict__ emb,
    u16* __restrict__ W1f, u16* __restrict__ W2f, u16* __restrict__ Woutf,
    float* __restrict__ bias1, float* __restrict__ bias2, u16* __restrict__ emb_bf,
    unsigned* __restrict__ bar)
{
    const int i0 = blockIdx.x * 256 + threadIdx.x;
    const int stride = gridDim.x * 256;
    for (int i = i0; i < 1024; i += stride)
        __hip_atomic_store(bar + i, 0u, __ATOMIC_RELAXED, __HIP_MEMORY_SCOPE_AGENT);
    for (int i = i0; i < 1152 * 2048; i += stride) {
        int k = i >> 11, n = i & 2047;
        float v = (k < 640) ? w_ih1[n * 640 + k] : w_hh1[n * 512 + (k - 640)];
        W1f[((size_t)(k >> 3) * 2048 + n) * 8 + (k & 7)] = f2bf(v);
    }
    for (int i = i0; i < 640 * 512; i += stride) {
        int k = i >> 9, n = i & 511;
        float v = (k < 512) ? w_ih2[n * 512 + k] : w_hh2[n * 128 + (k - 512)];
        W2f[((size_t)(k >> 3) * 512 + n) * 8 + (k & 7)] = f2bf(v);
    }
    for (int i = i0; i < 256 * 1024; i += stride) {
        int k = i >> 10, n = i & 1023;
        float v = (n < VOC) ? w_out[n * 256 + k] : 0.f;
        Woutf[((size_t)(k >> 3) * 1024 + n) * 8 + (k & 7)] = f2bf(v);
    }
    for (int i = i0; i < 2048; i += stride) bias1[i] = b_ih1[i] + b_hh1[i];
    for (int i = i0; i < 512; i += stride) bias2[i] = b_ih2[i] + b_hh2[i];
    for (int i = i0; i < VOC * H_; i += stride) emb_bf[i] = f2bf(emb[i]);
}

// key [S,B,K] f32 -> key_bf [B,S,K] bf16 ; values likewise
__global__ __launch_bounds__(256) void conv_kv_kernel(
    const float* __restrict__ key, const float* __restrict__ values,
    u16* __restrict__ key_bf, u16* __restrict__ val_bf)
{
    const int i0 = blockIdx.x * 256 + threadIdx.x;
    const int stride = gridDim.x * 256;
    for (int i = i0; i < S_ * B_ * K_; i += stride) {
        int s = i >> 14;
        int r = i & 16383;
        int b = r >> 7, k = r & 127;
        size_t d = ((size_t)b * S_ + s) * K_ + k;
        key_bf[d] = f2bf(key[i]);
        val_bf[d] = f2bf(values[i]);
    }
}

// ---------------- persistent pipelined decoder, point-to-point flags ----------------
// 160 WGs x 256 threads. wg<128 "row-WG" (L1 col-slice + attention row b=wg);
// wg>=128 "L2-WG" (LSTM2 GEMM tile). Per step:
//   P_A row (wait flagC quarter): finish gates1(t) + pointwise -> h1(t); set flagA
//   P_B row: emb-part gates1(t+1); (wait flagA quarter) h1 stage + h1-part
//   P_B L2  (wait flagA quarter): gates2(t) -> h2(t); set flagB
//   P_C row (wait flagB quarter-8): attention(t) -> ctx(t); set flagC
//   P_C L2  (wait flagB quarter-8): partial gates2(t+1) h2-part
// WAR safety: CT/H1 single-buffer overwrites at t+1 are transitively gated behind
// all step-t readers via the flagC->flagA->flagB dependency chain; H2 ping-pongs.
__global__ __launch_bounds__(256, 1) void decoder_kernel(
    const u16* __restrict__ emb_bf, const int* __restrict__ text,
    const u16* __restrict__ W1f, const float* __restrict__ bias1,
    const u16* __restrict__ W2f, const float* __restrict__ bias2,
    const u16* __restrict__ key_bf, const u16* __restrict__ val_bf,
    const int* __restrict__ lens,
    u16* __restrict__ CT, u16* __restrict__ H1, u16* __restrict__ H2,
    u16* __restrict__ Hc, unsigned* __restrict__ bar)
{
    extern __shared__ char smem[];
    u16*   vshare = (u16*)smem;                     // [500][128] bf16 (row-WGs only)
    char*  alias  = smem + VSH_BYTES;               // phase-disjoint union:
    u16*   h1st   = (u16*)alias;                    //   P_B: staged h1 [32][520]
    float* Gb     = (float*)alias;                  //   P_A / L2-P_B: gates [32][65]
    float* ebuf   = (float*)alias;                  //   P_C: energies [512]
    float* cbuf   = (float*)(alias + 2048);         //   P_C: ctx partials [4][128]
    float* h2s    = (float*)(alias + 4096);         //   P_C: query [128]
    float* redm   = (float*)(alias + 4608);         //   P_C: reductions [16]

    const int wg = blockIdx.x;
    const int tid = threadIdx.x;
    const int lane = tid & 63, wv = tid >> 6;       // wv = wave = gate index
    const int lrow = lane & 15, lk = lane >> 4;
    const bool isrow = wg < NROW;

    const int mh1 = wg >> 5, hg1 = wg & 31;         // row-WG L1 mapping
    const int n1 = wv * 512 + hg1 * 16 + lrow;
    const int l2 = wg - NROW;
    const int q2 = l2 >> 3, hg2 = l2 & 7;           // L2-WG mapping
    const int n2 = wv * 128 + hg2 * 16 + lrow;
    const int b  = wg;                              // attn batch row (row-WGs)
    const int mylen = isrow ? lens[b] : 0;

    float c1r[2] = {0.f, 0.f};                      // LSTM1 cell state
    float c2r[2] = {0.f, 0.f};                      // LSTM2 cell state
    f32x4 acc1[2] = {{0,0,0,0},{0,0,0,0}};          // partial gates1 (persistent)
    f32x4 acc2[2] = {{0,0,0,0},{0,0,0,0}};          // partial gates2 (persistent)

    // ---- init: zero state (sc1); row-WGs stage values[b] into LDS ----
    {
        int i0 = wg * 256 + tid, stride = NWG * 256;
        for (int i = i0; i < B_ * V_ / 2; i += stride) st_state4(CT + 2 * i, 0u);
        for (int i = i0; i < B_ * H_ / 2; i += stride) st_state4(H1 + 2 * i, 0u);
        for (int i = i0; i < B_ * K_;     i += stride) st_state4(H2 + 2 * i, 0u); // both bufs
        if (isrow) {
            const u16* vp = val_bf + (size_t)b * S_ * V_;
            for (int i = tid; i < (S_ * V_) / 8; i += 256)
                *reinterpret_cast<short8*>(vshare + i * 8) =
                    *reinterpret_cast<const short8*>(vp + (size_t)i * 8);
        }
    }
    set_flag(bar + FINIT + wg, 1u);
    wait_flags(bar + FINIT, NWG, 1u);
    // prologue partials are exactly 0: emb row0 zeros, h1(-1)=h2(-1)=0.

    for (int t = 0; t < NSTEP; ++t) {
        const int nxt = (t & 1) ^ 1;
        u16* H2n = H2 + (size_t)nxt * B_ * K_;
        const unsigned tg = (unsigned)(t + 1);

        if (isrow) {
            // ======== P_A: finish gates1(t) + LSTM1 pointwise ========
            wait_flags(bar + FC + mh1 * 32, 32, (unsigned)t);   // ctx(t-1) ready
            int grow[2];
#pragma unroll
            for (int rt = 0; rt < 2; ++rt) grow[rt] = mh1 * 32 + rt * 16 + lrow;
#pragma unroll
            for (int kc = 16; kc < 20; ++kc) {                  // ctx-part k[512,640)
                int k = kc * 32 + lk * 8;
                short8 bw = *reinterpret_cast<const short8*>(W1f + ((size_t)(k >> 3) * 2048 + n1) * 8);
#pragma unroll
                for (int rt = 0; rt < 2; ++rt) {
                    short8 a = ld_state16(CT + grow[rt] * V_ + (k - 512));
                    acc1[rt] = mfma16(a, bw, acc1[rt]);
                }
            }
            float bv = bias1[n1];
#pragma unroll
            for (int rt = 0; rt < 2; ++rt)
#pragma unroll
                for (int j = 0; j < 4; ++j)
                    Gb[(rt * 16 + lk * 4 + j) * 65 + wv * 16 + lrow] = acc1[rt][j] + bv;
            __syncthreads();
            {
                int rb = tid >> 3, j0 = (tid & 7) * 2;
                int bb = mh1 * 32 + rb;
                float gi0 = Gb[rb * 65 + j0],      gf0 = Gb[rb * 65 + 16 + j0];
                float gg0 = Gb[rb * 65 + 32 + j0], go0 = Gb[rb * 65 + 48 + j0];
                float gi1 = Gb[rb * 65 + j0 + 1],      gf1 = Gb[rb * 65 + 16 + j0 + 1];
                float gg1 = Gb[rb * 65 + 32 + j0 + 1], go1 = Gb[rb * 65 + 48 + j0 + 1];
                float cn0 = sigm(gf0) * c1r[0] + sigm(gi0) * tanh_f(gg0);
                float cn1 = sigm(gf1) * c1r[1] + sigm(gi1) * tanh_f(gg1);
                c1r[0] = cn0; c1r[1] = cn1;
                st_pair(H1 + bb * H_ + hg1 * 16 + j0,
                        sigm(go0) * tanh_f(cn0), sigm(go1) * tanh_f(cn1));
            }
            set_flag(bar + FA + wg, tg);                        // h1(t) ready

            // ======== P_B: partial gates1(t+1) ========
            acc1[0] = (f32x4){0,0,0,0}; acc1[1] = (f32x4){0,0,0,0};
            const u16* aemb[2];
#pragma unroll
            for (int rt = 0; rt < 2; ++rt) {
                int tok = text[(t + 1) * B_ + grow[rt]];
                aemb[rt] = emb_bf + (size_t)tok * H_;
            }
            // emb-part k[0,512) BEFORE the h1 wait (text-only dependency)
#pragma unroll 4
            for (int kc = 0; kc < 16; ++kc) {
                int k = kc * 32 + lk * 8;
                short8 bw = *reinterpret_cast<const short8*>(W1f + ((size_t)(k >> 3) * 2048 + n1) * 8);
#pragma unroll
                for (int rt = 0; rt < 2; ++rt) {
                    short8 a = *reinterpret_cast<const short8*>(aemb[rt] + k);
                    acc1[rt] = mfma16(a, bw, acc1[rt]);
                }
            }
            wait_flags(bar + FA + mh1 * 32, 32, tg);            // quarter h1(t) ready
            {
                const u16* src = H1 + (size_t)(mh1 * 32) * H_;
#pragma unroll
                for (int it = 0; it < 8; ++it) {
                    int c = it * 256 + tid;
                    int row = c >> 6, col = (c & 63) * 8;
                    u64 lo = ld_state8(src + (size_t)row * H_ + col);
                    u64 hi = ld_state8(src + (size_t)row * H_ + col + 4);
                    u64* dst = (u64*)(h1st + row * H1ST_STRIDE + col);
                    dst[0] = lo; dst[1] = hi;
                }
            }
            __syncthreads();
            // h1-part k[640,1152) from LDS stage
#pragma unroll 4
            for (int kc = 20; kc < 36; ++kc) {
                int k = kc * 32 + lk * 8;
                short8 bw = *reinterpret_cast<const short8*>(W1f + ((size_t)(k >> 3) * 2048 + n1) * 8);
#pragma unroll
                for (int rt = 0; rt < 2; ++rt) {
                    short8 a = *reinterpret_cast<const short8*>(
                        h1st + (rt * 16 + lrow) * H1ST_STRIDE + (kc - 20) * 32 + lk * 8);
                    acc1[rt] = mfma16(a, bw, acc1[rt]);
                }
            }

            // ======== P_C: attention(t) ========
            wait_flags(bar + FB + mh1 * 8, 8, tg);              // h2(t) quarter ready
            u16* Hc_t = Hc + (size_t)t * B_ * 256;
            if (tid < 64) {
                unsigned v = ld_state4(H2n + b * K_ + 2 * tid);
                h2s[2 * tid]     = bf2f((u16)(v & 0xffffu));
                h2s[2 * tid + 1] = bf2f((u16)(v >> 16));
                *reinterpret_cast<unsigned*>(Hc_t + b * 256 + 2 * tid) = v;
            }
            __syncthreads();

            for (int s = tid; s < 512; s += 256) {
                float e = -1e9f;
                if (s < S_) {
                    const u16* kp = key_bf + ((size_t)b * S_ + s) * K_;
                    float a = 0.f;
#pragma unroll
                    for (int kk = 0; kk < K_; kk += 8) {
                        short8 kv = *reinterpret_cast<const short8*>(kp + kk);
#pragma unroll
                        for (int j = 0; j < 8; ++j)
                            a += bf2f((u16)kv[j]) * h2s[kk + j];
                    }
                    e = (s < mylen) ? a : -1e9f;
                }
                ebuf[s] = e;
            }
            __syncthreads();

            float m = fmaxf(ebuf[tid], ebuf[tid + 256]);
#pragma unroll
            for (int off = 32; off > 0; off >>= 1) m = fmaxf(m, __shfl_down(m, off));
            if (lane == 0) redm[wv] = m;
            __syncthreads();
            const float maxv = fmaxf(fmaxf(redm[0], redm[1]), fmaxf(redm[2], redm[3]));

            float psum = 0.f;
            for (int s = tid; s < 512; s += 256) {
                float pv = __expf(ebuf[s] - maxv);
                ebuf[s] = pv;
                psum += pv;
            }
#pragma unroll
            for (int off = 32; off > 0; off >>= 1) psum += __shfl_down(psum, off);
            if (lane == 0) redm[4 + wv] = psum;
            __syncthreads();
            const float rinv = 1.f / (redm[4] + redm[5] + redm[6] + redm[7]);

            const int s0 = wv * 125;
            float p0 = 0.f, p1 = 0.f;
            for (int s = s0; s < s0 + 125; ++s) {
                float w = ebuf[s];
                unsigned pk = *reinterpret_cast<const unsigned*>(vshare + s * V_ + lane * 2);
                p0 += w * bf2f((u16)(pk & 0xffffu));
                p1 += w * bf2f((u16)(pk >> 16));
            }
            cbuf[wv * V_ + lane * 2]     = p0;
            cbuf[wv * V_ + lane * 2 + 1] = p1;
            __syncthreads();

            if (tid < 64) {
                int v0 = 2 * tid, v1 = 2 * tid + 1;
                float ctx0 = (cbuf[v0] + cbuf[V_ + v0] + cbuf[2 * V_ + v0] + cbuf[3 * V_ + v0]) * rinv;
                float ctx1 = (cbuf[v1] + cbuf[V_ + v1] + cbuf[2 * V_ + v1] + cbuf[3 * V_ + v1]) * rinv;
                st_pair(CT + b * V_ + v0, ctx0, ctx1);
                *reinterpret_cast<unsigned*>(Hc_t + b * 256 + K_ + v0) =
                    (unsigned)f2bf(ctx0) | ((unsigned)f2bf(ctx1) << 16);
            }
            set_flag(bar + FC + wg, tg);                        // ctx(t) ready
        } else {
            // ======== P_B: finish gates2(t) -> h2(t) ========
            wait_flags(bar + FA + q2 * 32, 32, tg);             // quarter h1(t) ready
            {
                const u16* src = H1 + (size_t)(q2 * 32) * H_;
#pragma unroll
                for (int it = 0; it < 8; ++it) {
                    int c = it * 256 + tid;
                    int row = c >> 6, col = (c & 63) * 8;
                    u64 lo = ld_state8(src + (size_t)row * H_ + col);
                    u64 hi = ld_state8(src + (size_t)row * H_ + col + 4);
                    u64* dst = (u64*)(h1st + row * H1ST_STRIDE + col);
                    dst[0] = lo; dst[1] = hi;
                }
            }
            __syncthreads();
            // h1-part k[0,512) into persistent acc2 (h2-part already there)
#pragma unroll 4
            for (int kc = 0; kc < 16; ++kc) {
                int k = kc * 32 + lk * 8;
                short8 bw = *reinterpret_cast<const short8*>(W2f + ((size_t)(k >> 3) * 512 + n2) * 8);
#pragma unroll
                for (int rt = 0; rt < 2; ++rt) {
                    short8 a = *reinterpret_cast<const short8*>(
                        h1st + (rt * 16 + lrow) * H1ST_STRIDE + kc * 32 + lk * 8);
                    acc2[rt] = mfma16(a, bw, acc2[rt]);
                }
            }
            float bv = bias2[n2];
            __syncthreads();   // h1st reads done; Gb may overwrite alias
#pragma unroll
            for (int rt = 0; rt < 2; ++rt)
#pragma unroll
                for (int j = 0; j < 4; ++j)
                    Gb[(rt * 16 + lk * 4 + j) * 65 + wv * 16 + lrow] = acc2[rt][j] + bv;
            __syncthreads();
            {
                int rb = tid >> 3, j0 = (tid & 7) * 2;
                int bb = q2 * 32 + rb;
                float gi0 = Gb[rb * 65 + j0],      gf0 = Gb[rb * 65 + 16 + j0];
                float gg0 = Gb[rb * 65 + 32 + j0], go0 = Gb[rb * 65 + 48 + j0];
                float gi1 = Gb[rb * 65 + j0 + 1],      gf1 = Gb[rb * 65 + 16 + j0 + 1];
                float gg1 = Gb[rb * 65 + 32 + j0 + 1], go1 = Gb[rb * 65 + 48 + j0 + 1];
                float cn0 = sigm(gf0) * c2r[0] + sigm(gi0) * tanh_f(gg0);
                float cn1 = sigm(gf1) * c2r[1] + sigm(gi1) * tanh_f(gg1);
                c2r[0] = cn0; c2r[1] = cn1;
                st_pair(H2n + bb * K_ + hg2 * 16 + j0,
                        sigm(go0) * tanh_f(cn0), sigm(go1) * tanh_f(cn1));
            }
            set_flag(bar + FB + l2, tg);                        // h2(t) ready

            // ======== P_C: partial gates2(t+1) h2-part ========
            wait_flags(bar + FB + q2 * 8, 8, tg);               // full quarter h2 rows
            acc2[0] = (f32x4){0,0,0,0}; acc2[1] = (f32x4){0,0,0,0};
#pragma unroll
            for (int kc = 16; kc < 20; ++kc) {
                int k = kc * 32 + lk * 8;
                short8 bw = *reinterpret_cast<const short8*>(W2f + ((size_t)(k >> 3) * 512 + n2) * 8);
#pragma unroll
                for (int rt = 0; rt < 2; ++rt) {
                    short8 a = ld_state16(H2n + (q2 * 32 + rt * 16 + lrow) * K_ + (k - 512));
                    acc2[rt] = mfma16(a, bw, acc2[rt]);
                }
            }
        }
    }
}

// ---------------- final: pred = Hc[31872,256] @ Wout^T + b_out ----------------
__global__ __launch_bounds__(256) void k4_kernel(
    const u16* __restrict__ Hc, const u16* __restrict__ Woutf,
    const float* __restrict__ b_out, float* __restrict__ out)
{
    const int bx = blockIdx.x;
    const int mt = bx >> 4, nt = bx & 15;
    const int tid = threadIdx.x;
    const int lane = tid & 63, g = tid >> 6;
    const int lrow = lane & 15, lk = lane >> 4;
    const int n = nt * 64 + g * 16 + lrow;
    const float bias = (n < VOC) ? b_out[n] : 0.f;

    f32x4 acc[8];
#pragma unroll
    for (int rt = 0; rt < 8; ++rt) acc[rt] = (f32x4){bias, bias, bias, bias};

#pragma unroll
    for (int kc = 0; kc < 8; ++kc) {
        int k = kc * 32 + lk * 8;
        short8 bw = *reinterpret_cast<const short8*>(Woutf + ((size_t)(k >> 3) * 1024 + n) * 8);
#pragma unroll
        for (int rt = 0; rt < 8; ++rt) {
            int R = mt * 128 + rt * 16 + lrow;
            short8 a = *reinterpret_cast<const short8*>(Hc + (size_t)R * 256 + k);
            acc[rt] = mfma16(a, bw, acc[rt]);
        }
    }
    if (n < VOC) {
#pragma unroll
        for (int rt = 0; rt < 8; ++rt)
#pragma unroll
            for (int j = 0; j < 4; ++j) {
                int R = mt * 128 + rt * 16 + lk * 4 + j;
                int tt = R >> 7, bb = R & 127;
                out[((size_t)bb * NSTEP + tt) * VOC + n] = acc[rt][j];
            }
    }
}

// ---------------- host ----------------
extern "C" void kernel_launch(void* const* d_in, const int* in_sizes, int n_in,
                              void* d_out, int out_size, void* d_ws, size_t ws_size,
                              hipStream_t stream)
{
    const float* key    = (const float*)d_in[0];
    const float* values = (const float*)d_in[1];
    const int*   lens   = (const int*)d_in[2];
    const int*   text   = (const int*)d_in[3];
    const float* emb    = (const float*)d_in[4];
    const float* w_ih1  = (const float*)d_in[5];
    const float* w_hh1  = (const float*)d_in[6];
    const float* b_ih1  = (const float*)d_in[7];
    const float* b_hh1  = (const float*)d_in[8];
    const float* w_ih2  = (const float*)d_in[9];
    const float* w_hh2  = (const float*)d_in[10];
    const float* b_ih2  = (const float*)d_in[11];
    const float* b_hh2  = (const float*)d_in[12];
    const float* w_out  = (const float*)d_in[13];
    const float* b_out  = (const float*)d_in[14];

    char* p = (char*)d_ws;
    auto alloc = [&](size_t bytes) -> char* {
        char* r = p;
        p += (bytes + 255) & ~(size_t)255;
        return r;
    };
    u16*      key_bf = (u16*)     alloc((size_t)B_ * S_ * K_ * 2);
    u16*      val_bf = (u16*)     alloc((size_t)B_ * S_ * V_ * 2);
    u16*      emb_bf = (u16*)     alloc((size_t)VOC * H_ * 2);
    u16*      W1f    = (u16*)     alloc((size_t)1152 * 2048 * 2);
    u16*      W2f    = (u16*)     alloc((size_t)640 * 512 * 2);
    u16*      Woutf  = (u16*)     alloc((size_t)256 * 1024 * 2);
    float*    bias1  = (float*)   alloc(2048 * 4);
    float*    bias2  = (float*)   alloc(512 * 4);
    u16*      CT     = (u16*)     alloc((size_t)B_ * V_ * 2);       // single buffer
    u16*      H1     = (u16*)     alloc((size_t)B_ * H_ * 2);       // single buffer
    u16*      H2     = (u16*)     alloc((size_t)2 * B_ * K_ * 2);   // ping-pong
    u16*      Hc     = (u16*)     alloc((size_t)NSTEP * B_ * 256 * 2);
    unsigned* bar    = (unsigned*)alloc(4096);
    (void)ws_size; (void)in_sizes; (void)n_in; (void)out_size;

    hipFuncSetAttribute((const void*)decoder_kernel,
                        hipFuncAttributeMaxDynamicSharedMemorySize, SMEM_BYTES);

    pack_kernel<<<512, 256, 0, stream>>>(w_ih1, w_hh1, b_ih1, b_hh1,
                                         w_ih2, w_hh2, b_ih2, b_hh2,
                                         w_out, emb, W1f, W2f, Woutf, bias1, bias2, emb_bf,
                                         bar);
    conv_kv_kernel<<<4096, 256, 0, stream>>>(key, values, key_bf, val_bf);

    decoder_kernel<<<NWG, 256, SMEM_BYTES, stream>>>(emb_bf, text, W1f, bias1, W2f, bias2,
                                                     key_bf, val_bf, lens, CT, H1, H2, Hc, bar);

    k4_kernel<<<NSTEP * 16, 256, 0, stream>>>(Hc, Woutf, b_out, (float*)d_out);
}